// Round 7
// baseline (753.598 us; speedup 1.0000x reference)
//
#include <hip/hip_runtime.h>
#include <hip/hip_fp16.h>

#define NB 512
#define NT 512
#define NWAVES (NB * (NT / 64))

typedef _Float16 half8 __attribute__((ext_vector_type(8)));
typedef float f32x4 __attribute__((ext_vector_type(4)));
typedef unsigned long long ull;

// device-scope grid barrier; bars[k] used once per launch (memset to 0 each call)
__device__ __forceinline__ void grid_barrier(int* bar) {
    __syncthreads();
    if (threadIdx.x == 0) {
        __hip_atomic_fetch_add(bar, 1, __ATOMIC_ACQ_REL, __HIP_MEMORY_SCOPE_AGENT);
        while (__hip_atomic_load(bar, __ATOMIC_ACQUIRE,
                                 __HIP_MEMORY_SCOPE_AGENT) < NB) {}
    }
    __syncthreads();
}

__device__ __forceinline__ float4 h4_to_f4(uint2 m) {
    float2 f0 = __half22float2(*reinterpret_cast<const __half2*>(&m.x));
    float2 f1 = __half22float2(*reinterpret_cast<const __half2*>(&m.y));
    return make_float4(f0.x, f0.y, f1.x, f1.y);
}

// CSR gather: acc = dn*t[self] + sum_e dis[src_e]*t[src_e], lane holds 4 feats
__device__ __forceinline__ float4 gather_row(const uint2* __restrict__ tin,
                                             const int* __restrict__ rowptr,
                                             const ull* __restrict__ rec,
                                             int wid, int lane, float dn) {
    float4 self = h4_to_f4(tin[(size_t)wid * 64 + lane]);
    float4 acc = make_float4(dn * self.x, dn * self.y, dn * self.z, dn * self.w);
    int e = rowptr[wid], end = rowptr[wid + 1];
    for (; e + 3 < end; e += 4) {
        ull r0 = rec[e], r1 = rec[e + 1], r2 = rec[e + 2], r3 = rec[e + 3];
        float4 f0 = h4_to_f4(tin[(size_t)(unsigned)r0 * 64 + lane]);
        float4 f1 = h4_to_f4(tin[(size_t)(unsigned)r1 * 64 + lane]);
        float4 f2 = h4_to_f4(tin[(size_t)(unsigned)r2 * 64 + lane]);
        float4 f3 = h4_to_f4(tin[(size_t)(unsigned)r3 * 64 + lane]);
        float d0 = __uint_as_float((unsigned)(r0 >> 32));
        float d1 = __uint_as_float((unsigned)(r1 >> 32));
        float d2 = __uint_as_float((unsigned)(r2 >> 32));
        float d3 = __uint_as_float((unsigned)(r3 >> 32));
        acc.x = fmaf(d0, f0.x, fmaf(d1, f1.x, fmaf(d2, f2.x, fmaf(d3, f3.x, acc.x))));
        acc.y = fmaf(d0, f0.y, fmaf(d1, f1.y, fmaf(d2, f2.y, fmaf(d3, f3.y, acc.y))));
        acc.z = fmaf(d0, f0.z, fmaf(d1, f1.z, fmaf(d2, f2.z, fmaf(d3, f3.z, acc.z))));
        acc.w = fmaf(d0, f0.w, fmaf(d1, f1.w, fmaf(d2, f2.w, fmaf(d3, f3.w, acc.w))));
    }
    for (; e < end; ++e) {
        ull r = rec[e];
        float4 f = h4_to_f4(tin[(size_t)(unsigned)r * 64 + lane]);
        float ds = __uint_as_float((unsigned)(r >> 32));
        acc.x = fmaf(ds, f.x, acc.x); acc.y = fmaf(ds, f.y, acc.y);
        acc.z = fmaf(ds, f.z, acc.z); acc.w = fmaf(ds, f.w, acc.w);
    }
    return acc;
}

__global__ __launch_bounds__(NT, 4)
void mega(const float* __restrict__ x, const int* __restrict__ ei,
          const float* __restrict__ Wc1, const float* __restrict__ bc1,
          const float* __restrict__ Wc2, const float* __restrict__ bc2,
          const float* __restrict__ Wp,  const float* __restrict__ bp,
          const float* __restrict__ Wv1, const float* __restrict__ bv1,
          const float* __restrict__ Wv2, const float* __restrict__ bv2,
          const float* __restrict__ Wvh, const float* __restrict__ bvh,
          int* cnt, int* flags, int* bars, int* pos, int* rowptr, float* dis,
          ull* rec, __half* Wch, __half* Wvh2, __half* tbuf, __half* hbuf,
          float* outm, float* outv, int N, int E) {
    __shared__ float smemf[512];
    __shared__ int s_prev;
    const int tid = threadIdx.x, bid = blockIdx.x;
    const int gw = bid * (NT / 64) + (tid >> 6);
    const int lane = tid & 63;

    // ============ phase A: W2->fp16, edge count (+pos), feat1 ====================
    {
        int i = bid * NT + tid;
        if (i < 128 * 128) {
            Wch[i]  = __float2half_rn(Wc2[i]);
            Wvh2[i] = __float2half_rn(Wv2[i]);
        }
    }
    for (int e = bid * NT + tid; e < E; e += NB * NT) {
        int d = ei[E + e];
        pos[e] = atomicAdd(&cnt[d], 1);
    }
    {   // feat1: t1[n,0:128]=x@Wc1^T, t1[n,128:256]=x@Wv1^T (unscaled), fp16
        float (*xt)[16][16] = (float (*)[16][16])smemf;
        int hb = tid >> 8, ht = tid & 255;                 // half-block, thread
        const int ngroups = (N + 15) / 16;
        const int iters = (ngroups + 2 * NB - 1) / (2 * NB);
        const float* wrow = (ht < 128) ? (Wc1 + ht * 16) : (Wv1 + (ht - 128) * 16);
        float4 w0 = *(const float4*)(wrow + 0);
        float4 w1 = *(const float4*)(wrow + 4);
        float4 w2 = *(const float4*)(wrow + 8);
        float4 w3 = *(const float4*)(wrow + 12);
        for (int it = 0; it < iters; ++it) {
            int g = bid * 2 + hb + it * 2 * NB;
            __syncthreads();
            if (g < ngroups) {
                int n = ht >> 4, k = ht & 15;
                int node = g * 16 + n;
                xt[hb][n][k] = (node < N) ? x[node * 16 + k] : 0.f;
            }
            __syncthreads();
            if (g < ngroups) {
                for (int n = 0; n < 16; ++n) {
                    int node = g * 16 + n;
                    if (node >= N) break;
                    const float* xr = xt[hb][n];
                    float s = w0.x * xr[0] + w0.y * xr[1] + w0.z * xr[2] + w0.w * xr[3]
                            + w1.x * xr[4] + w1.y * xr[5] + w1.z * xr[6] + w1.w * xr[7]
                            + w2.x * xr[8] + w2.y * xr[9] + w2.z * xr[10] + w2.w * xr[11]
                            + w3.x * xr[12] + w3.y * xr[13] + w3.z * xr[14] + w3.w * xr[15];
                    tbuf[(size_t)node * 256 + ht] = __float2half_rn(s);
                }
            }
        }
    }
    grid_barrier(bars + 0);

    // ============ phase B: scan (13 blocks, decoupled lookback) ==================
    if (bid < 13) {
        int* sd = (int*)smemf;
        int base = bid * (NT * 8) + tid * 8;
        int v[8];
        int s = 0;
#pragma unroll
        for (int k = 0; k < 8; ++k) {
            int i = base + k;
            v[k] = (i < N) ? cnt[i] : 0;
            s += v[k];
        }
        sd[tid] = s;
        __syncthreads();
        for (int off = 1; off < NT; off <<= 1) {
            int t2 = 0;
            if (tid >= off) t2 = sd[tid - off];
            __syncthreads();
            sd[tid] += t2;
            __syncthreads();
        }
        int excl = sd[tid] - s;
        if (tid == 0) {
            int prev = 0;
            if (bid > 0) {
                int f;
                while ((f = __hip_atomic_load(flags + bid - 1, __ATOMIC_ACQUIRE,
                                              __HIP_MEMORY_SCOPE_AGENT)) == 0) {}
                prev = f - 1;
            }
            __hip_atomic_store(flags + bid, prev + sd[NT - 1] + 1,
                               __ATOMIC_RELEASE, __HIP_MEMORY_SCOPE_AGENT);
            s_prev = prev;
        }
        __syncthreads();
        int run = s_prev + excl;
#pragma unroll
        for (int k = 0; k < 8; ++k) {
            int i = base + k;
            if (i < N) {
                rowptr[i] = run;
                dis[i] = rsqrtf((float)(v[k] + 1));
                run += v[k];
            }
        }
        if (bid == 0 && tid == 0) rowptr[N] = E;
    }
    grid_barrier(bars + 1);

    // ============ phase C: CSR fill, rec[p] = {dis[src] : src} ===================
    for (int e = bid * NT + tid; e < E; e += NB * NT) {
        int s = ei[e], d = ei[E + e];
        rec[rowptr[d] + pos[e]] = ((ull)__float_as_uint(dis[s]) << 32) | (unsigned)s;
    }
    grid_barrier(bars + 2);

    // ============ phase D: agg1 -> hbuf (fp16) ===================================
    for (int wid = gw; wid < N; wid += NWAVES) {
        float dn = dis[wid];
        float4 acc = gather_row((const uint2*)tbuf, rowptr, rec, wid, lane, dn);
        int f = lane * 4;
        float4 b = (f < 128) ? *(const float4*)(bc1 + f)
                             : *(const float4*)(bv1 + f - 128);
        __half2 h0 = __floats2half2_rn(fmaxf(fmaf(dn, acc.x, b.x), 0.f),
                                       fmaxf(fmaf(dn, acc.y, b.y), 0.f));
        __half2 h1 = __floats2half2_rn(fmaxf(fmaf(dn, acc.z, b.z), 0.f),
                                       fmaxf(fmaf(dn, acc.w, b.w), 0.f));
        uint2 o;
        o.x = *reinterpret_cast<unsigned*>(&h0);
        o.y = *reinterpret_cast<unsigned*>(&h1);
        ((uint2*)hbuf)[(size_t)wid * 64 + lane] = o;
    }
    grid_barrier(bars + 3);

    // ============ phase E: feat2 MFMA, t2 = h1 @ W^T -> tbuf (fp16) ==============
    {
        int quad = lane >> 4, l16 = lane & 15;
        const int nt16 = (N + 15) / 16;            // N divisible by 16 here
        for (int item = gw; item < 2 * nt16; item += NWAVES) {
            int br = (item >= nt16) ? 1 : 0;
            int tile = item - br * nt16;
            int n0 = tile * 16;
            const _Float16* W = (const _Float16*)(br ? Wvh2 : Wch);
            int koff = br * 128;
            const _Float16* arow = (const _Float16*)hbuf
                                 + (size_t)(n0 + l16) * 256 + koff + quad * 8;
            half8 a0 = *(const half8*)(arow + 0);
            half8 a1 = *(const half8*)(arow + 32);
            half8 a2 = *(const half8*)(arow + 64);
            half8 a3 = *(const half8*)(arow + 96);
            _Float16* to = (_Float16*)tbuf;
#pragma unroll
            for (int jj = 0; jj < 8; ++jj) {
                const _Float16* wr = W + (size_t)(jj * 16 + l16) * 128 + quad * 8;
                half8 b0 = *(const half8*)(wr + 0);
                half8 b1 = *(const half8*)(wr + 32);
                half8 b2 = *(const half8*)(wr + 64);
                half8 b3 = *(const half8*)(wr + 96);
                f32x4 acc = {0.f, 0.f, 0.f, 0.f};
                acc = __builtin_amdgcn_mfma_f32_16x16x32_f16(a0, b0, acc, 0, 0, 0);
                acc = __builtin_amdgcn_mfma_f32_16x16x32_f16(a1, b1, acc, 0, 0, 0);
                acc = __builtin_amdgcn_mfma_f32_16x16x32_f16(a2, b2, acc, 0, 0, 0);
                acc = __builtin_amdgcn_mfma_f32_16x16x32_f16(a3, b3, acc, 0, 0, 0);
                int fo = koff + jj * 16 + l16;
#pragma unroll
                for (int r = 0; r < 4; ++r) {
                    int node = n0 + quad * 4 + r;
                    if (node < N)
                        to[(size_t)node * 256 + fo] = (_Float16)acc[r];
                }
            }
        }
    }
    grid_barrier(bars + 4);

    // ============ phase F: agg2 + heads ==========================================
    for (int wid = gw; wid < N; wid += NWAVES) {
        float dn = dis[wid];
        float4 acc = gather_row((const uint2*)tbuf, rowptr, rec, wid, lane, dn);
        int f = lane * 4;
        float4 b = (f < 128) ? *(const float4*)(bc2 + f)
                             : *(const float4*)(bv2 + f - 128);
        float hx = fmaxf(fmaf(dn, acc.x, b.x), 0.f);
        float hy = fmaxf(fmaf(dn, acc.y, b.y), 0.f);
        float hz = fmaxf(fmaf(dn, acc.z, b.z), 0.f);
        float hw = fmaxf(fmaf(dn, acc.w, b.w), 0.f);
        const float* wptr = (lane < 32) ? (Wp + lane * 4) : (Wvh + (lane - 32) * 4);
        float4 w = *(const float4*)wptr;
        float p = hx * w.x + hy * w.y + hz * w.z + hw * w.w;
        for (int off = 16; off; off >>= 1) p += __shfl_down(p, off, 32);
        if (lane == 0)  outm[wid] = p + bp[0];
        if (lane == 32) outv[wid] = p + bvh[0];
    }
}

// ---------------- launch ---------------------------------------------------------

extern "C" void kernel_launch(void* const* d_in, const int* in_sizes, int n_in,
                              void* d_out, int out_size, void* d_ws, size_t ws_size,
                              hipStream_t stream) {
    const float* x   = (const float*)d_in[0];
    const int*   ei  = (const int*)  d_in[1];
    const float* Wc1 = (const float*)d_in[2];
    const float* bc1 = (const float*)d_in[3];
    const float* Wc2 = (const float*)d_in[4];
    const float* bc2 = (const float*)d_in[5];
    const float* Wp  = (const float*)d_in[6];
    const float* bp  = (const float*)d_in[7];
    const float* Wv1 = (const float*)d_in[8];
    const float* bv1 = (const float*)d_in[9];
    const float* Wv2 = (const float*)d_in[10];
    const float* bv2 = (const float*)d_in[11];
    const float* Wvh = (const float*)d_in[12];
    const float* bvh = (const float*)d_in[13];

    const int N = in_sizes[0] / 16;   // 50000
    const int E = in_sizes[1] / 2;    // 800000
    const int Npad = (N + 63) & ~63;

    size_t off = 0;
    auto alloc = [&](size_t bytes) -> void* {
        void* p = (char*)d_ws + off;
        off += (bytes + 255) & ~(size_t)255;
        return p;
    };
    // cnt, flags, bars contiguous -> one memset zeroes all control state
    int*    cnt    = (int*)alloc((size_t)(N + 64) * sizeof(int));
    int*    flags  = cnt + N;        // 16 slots
    int*    bars   = cnt + N + 16;   // 16 slots
    int*    pos    = (int*)alloc((size_t)E * sizeof(int));
    int*    rowptr = (int*)alloc((size_t)(N + 1) * sizeof(int));
    float*  dis    = (float*)alloc((size_t)Npad * sizeof(float));
    ull*    rec    = (ull*)alloc((size_t)E * sizeof(ull));                // 6.4 MB
    __half* Wch    = (__half*)alloc(128 * 128 * sizeof(__half));
    __half* Wvh2   = (__half*)alloc(128 * 128 * sizeof(__half));
    __half* tbuf   = (__half*)alloc((size_t)Npad * 256 * sizeof(__half)); // 25.6 MB
    __half* hbuf   = (__half*)alloc((size_t)Npad * 256 * sizeof(__half)); // 25.6 MB

    float* outm = (float*)d_out;
    float* outv = outm + N;

    (void)hipMemsetAsync(cnt, 0, (size_t)(N + 64) * sizeof(int), stream);
    mega<<<NB, NT, 0, stream>>>(x, ei, Wc1, bc1, Wc2, bc2, Wp, bp,
                                Wv1, bv1, Wv2, bv2, Wvh, bvh,
                                cnt, flags, bars, pos, rowptr, dis,
                                rec, Wch, Wvh2, tbuf, hbuf,
                                outm, outv, N, E);
}

// Round 8
// 307.710 us; speedup vs baseline: 2.4491x; 2.4491x over previous
//
#include <hip/hip_runtime.h>
#include <hip/hip_bf16.h>
#include <hip/hip_fp16.h>

#define TPB 256

typedef _Float16 half8 __attribute__((ext_vector_type(8)));
typedef float f32x4 __attribute__((ext_vector_type(4)));
typedef unsigned long long ull;

// ---------------- fused prep: edge count (+pos), feat1 (unscaled), W2->fp16 ------

__global__ void fused_prep(const int* __restrict__ ei, int* __restrict__ cnt,
                           int* __restrict__ pos,
                           const float* __restrict__ x, const float* __restrict__ Wc1,
                           const float* __restrict__ Wv1, __half* __restrict__ tbuf,
                           const float* __restrict__ Wc2, const float* __restrict__ Wv2,
                           __half* __restrict__ Wch, __half* __restrict__ Wvh2,
                           int N, int E, int nbE, int nbF) {
    __shared__ float xt[16][16];
    int bid = blockIdx.x;
    int t = threadIdx.x;
    if (bid < nbE) {
        int e = bid * TPB + t;
        if (e < E) {
            int d = ei[E + e];
            pos[e] = atomicAdd(&cnt[d], 1);
        }
    } else if (bid < nbE + nbF) {
        int n0 = (bid - nbE) * 16;
        {
            int n = t >> 4, k = t & 15;
            int node = n0 + n;
            xt[n][k] = (node < N) ? x[node * 16 + k] : 0.f;
        }
        const float* wrow = (t < 128) ? (Wc1 + t * 16) : (Wv1 + (t - 128) * 16);
        float4 w0 = *(const float4*)(wrow + 0);
        float4 w1 = *(const float4*)(wrow + 4);
        float4 w2 = *(const float4*)(wrow + 8);
        float4 w3 = *(const float4*)(wrow + 12);
        __syncthreads();
        for (int n = 0; n < 16; ++n) {
            int node = n0 + n;
            if (node >= N) break;
            const float* xr = xt[n];
            float s = w0.x * xr[0] + w0.y * xr[1] + w0.z * xr[2] + w0.w * xr[3]
                    + w1.x * xr[4] + w1.y * xr[5] + w1.z * xr[6] + w1.w * xr[7]
                    + w2.x * xr[8] + w2.y * xr[9] + w2.z * xr[10] + w2.w * xr[11]
                    + w3.x * xr[12] + w3.y * xr[13] + w3.z * xr[14] + w3.w * xr[15];
            tbuf[(size_t)node * 256 + t] = __float2half_rn(s);
        }
    } else {
        int i = (bid - nbE - nbF) * TPB + t;
        if (i < 128 * 128) {
            Wch[i]  = __float2half_rn(Wc2[i]);
            Wvh2[i] = __float2half_rn(Wv2[i]);
        }
    }
}

// ---------------- single-kernel scan (decoupled lookback, 13 co-resident blocks) -

#define SCAN_T 1024
#define SCAN_PER 4

__global__ __launch_bounds__(1024)
void scan_lookback(const int* __restrict__ cnt, int* __restrict__ rowptr,
                   float* __restrict__ dis, int* __restrict__ flags,
                   int N, int E) {
    __shared__ int sd[SCAN_T];
    __shared__ int s_prev;
    int t = threadIdx.x, b = blockIdx.x;
    int base = b * (SCAN_T * SCAN_PER) + t * SCAN_PER;
    int v[SCAN_PER];
    int s = 0;
#pragma unroll
    for (int k = 0; k < SCAN_PER; ++k) {
        int i = base + k;
        v[k] = (i < N) ? cnt[i] : 0;
        s += v[k];
    }
    sd[t] = s;
    __syncthreads();
    for (int off = 1; off < SCAN_T; off <<= 1) {
        int x = 0;
        if (t >= off) x = sd[t - off];
        __syncthreads();
        sd[t] += x;
        __syncthreads();
    }
    int excl = sd[t] - s;
    if (t == 0) {
        int prev = 0;
        if (b > 0) {
            int f;
            while ((f = __hip_atomic_load(flags + b - 1, __ATOMIC_ACQUIRE,
                                          __HIP_MEMORY_SCOPE_AGENT)) == 0) {}
            prev = f - 1;
        }
        __hip_atomic_store(flags + b, prev + sd[SCAN_T - 1] + 1,
                           __ATOMIC_RELEASE, __HIP_MEMORY_SCOPE_AGENT);
        s_prev = prev;
    }
    __syncthreads();
    int run = s_prev + excl;
#pragma unroll
    for (int k = 0; k < SCAN_PER; ++k) {
        int i = base + k;
        if (i < N) {
            rowptr[i] = run;
            dis[i] = rsqrtf((float)(v[k] + 1));
            run += v[k];
        }
    }
    if (b == 0 && t == 0) rowptr[N] = E;
}

// ---------------- CSR fill (atomic-free): rec[e] = {dis[src] : src} --------------

__global__ void fill_csr(const int* __restrict__ ei, const int* __restrict__ rowptr,
                         const int* __restrict__ pos, const float* __restrict__ dis,
                         ull* __restrict__ rec, int E) {
    int e = blockIdx.x * TPB + threadIdx.x;
    if (e >= E) return;
    int s = ei[e], d = ei[E + e];
    int p = rowptr[d] + pos[e];
    rec[p] = ((ull)__float_as_uint(dis[s]) << 32) | (unsigned)s;
}

// ---------------- high-MLP sliced-wave aggregation -------------------------------
// wave = 2 nodes (lanes 0-31 / 32-63); lane = 16 B (8 fp16 feats), 32 lanes = row.
// 4 edges in flight per half-wave, edge records prefetched one batch ahead.
// acc a0..a7 = dn*t[self] + sum_e ds_e * t[src_e] for feats 8*sl .. 8*sl+7.

#define AGG_BODY                                                                    \
    int node = blockIdx.x * 8 + ((threadIdx.x >> 6) << 1) + ((threadIdx.x & 63) >> 5); \
    if (node >= N) return;                                                          \
    int sl = threadIdx.x & 31;                                                      \
    float dn = dis[node];                                                           \
    float a0, a1, a2, a3, a4, a5, a6, a7;                                           \
    {                                                                               \
        uint4 ms = tin[(size_t)node * 32 + sl];                                     \
        float2 s0 = __half22float2(*reinterpret_cast<const __half2*>(&ms.x));       \
        float2 s1 = __half22float2(*reinterpret_cast<const __half2*>(&ms.y));       \
        float2 s2 = __half22float2(*reinterpret_cast<const __half2*>(&ms.z));       \
        float2 s3 = __half22float2(*reinterpret_cast<const __half2*>(&ms.w));       \
        a0 = dn * s0.x; a1 = dn * s0.y; a2 = dn * s1.x; a3 = dn * s1.y;             \
        a4 = dn * s2.x; a5 = dn * s2.y; a6 = dn * s3.x; a7 = dn * s3.y;             \
    }                                                                               \
    int e = rowptr[node], end = rowptr[node + 1];                                   \
    const ull sent = (ull)(unsigned)node;  /* ds=+0 -> no contribution */           \
    ull r0 = (e + 0 < end) ? rec[e + 0] : sent;                                     \
    ull r1 = (e + 1 < end) ? rec[e + 1] : sent;                                     \
    ull r2 = (e + 2 < end) ? rec[e + 2] : sent;                                     \
    ull r3 = (e + 3 < end) ? rec[e + 3] : sent;                                     \
    for (; e < end; e += 4) {                                                       \
        uint4 m0 = tin[(size_t)(unsigned)r0 * 32 + sl];                             \
        uint4 m1 = tin[(size_t)(unsigned)r1 * 32 + sl];                             \
        uint4 m2 = tin[(size_t)(unsigned)r2 * 32 + sl];                             \
        uint4 m3 = tin[(size_t)(unsigned)r3 * 32 + sl];                             \
        float d0 = __uint_as_float((unsigned)(r0 >> 32));                           \
        float d1 = __uint_as_float((unsigned)(r1 >> 32));                           \
        float d2 = __uint_as_float((unsigned)(r2 >> 32));                           \
        float d3 = __uint_as_float((unsigned)(r3 >> 32));                           \
        int en = e + 4;                                                             \
        r0 = (en + 0 < end) ? rec[en + 0] : sent;                                   \
        r1 = (en + 1 < end) ? rec[en + 1] : sent;                                   \
        r2 = (en + 2 < end) ? rec[en + 2] : sent;                                   \
        r3 = (en + 3 < end) ? rec[en + 3] : sent;                                   \
        AGG_ACC(m0, d0) AGG_ACC(m1, d1) AGG_ACC(m2, d2) AGG_ACC(m3, d3)             \
    }

#define AGG_ACC(M, D)                                                               \
    {                                                                               \
        float2 f0 = __half22float2(*reinterpret_cast<const __half2*>(&M.x));        \
        float2 f1 = __half22float2(*reinterpret_cast<const __half2*>(&M.y));        \
        float2 f2 = __half22float2(*reinterpret_cast<const __half2*>(&M.z));        \
        float2 f3 = __half22float2(*reinterpret_cast<const __half2*>(&M.w));        \
        a0 = fmaf(D, f0.x, a0); a1 = fmaf(D, f0.y, a1);                             \
        a2 = fmaf(D, f1.x, a2); a3 = fmaf(D, f1.y, a3);                             \
        a4 = fmaf(D, f2.x, a4); a5 = fmaf(D, f2.y, a5);                             \
        a6 = fmaf(D, f3.x, a6); a7 = fmaf(D, f3.y, a7);                             \
    }

__global__ void agg1(const uint4* __restrict__ tin, const int* __restrict__ rowptr,
                     const ull* __restrict__ rec, const float* __restrict__ dis,
                     const float* __restrict__ bc, const float* __restrict__ bv,
                     uint4* __restrict__ hout, int N) {
    AGG_BODY
    int F = sl * 8;
    const float* bb = (F < 128) ? (bc + F) : (bv + F - 128);
    float4 bA = *(const float4*)bb;
    float4 bB = *(const float4*)(bb + 4);
    __half2 h0 = __floats2half2_rn(fmaxf(fmaf(dn, a0, bA.x), 0.f),
                                   fmaxf(fmaf(dn, a1, bA.y), 0.f));
    __half2 h1 = __floats2half2_rn(fmaxf(fmaf(dn, a2, bA.z), 0.f),
                                   fmaxf(fmaf(dn, a3, bA.w), 0.f));
    __half2 h2 = __floats2half2_rn(fmaxf(fmaf(dn, a4, bB.x), 0.f),
                                   fmaxf(fmaf(dn, a5, bB.y), 0.f));
    __half2 h3 = __floats2half2_rn(fmaxf(fmaf(dn, a6, bB.z), 0.f),
                                   fmaxf(fmaf(dn, a7, bB.w), 0.f));
    uint4 o;
    o.x = *reinterpret_cast<unsigned*>(&h0);
    o.y = *reinterpret_cast<unsigned*>(&h1);
    o.z = *reinterpret_cast<unsigned*>(&h2);
    o.w = *reinterpret_cast<unsigned*>(&h3);
    hout[(size_t)node * 32 + sl] = o;
}

__global__ void agg2(const uint4* __restrict__ tin, const int* __restrict__ rowptr,
                     const ull* __restrict__ rec, const float* __restrict__ dis,
                     const float* __restrict__ bc, const float* __restrict__ bv,
                     const float* __restrict__ Wp, const float* __restrict__ bp,
                     const float* __restrict__ Wvh, const float* __restrict__ bvh,
                     float* __restrict__ outm, float* __restrict__ outv, int N) {
    AGG_BODY
    int F = sl * 8;
    const float* bb = (F < 128) ? (bc + F) : (bv + F - 128);
    float4 bA = *(const float4*)bb;
    float4 bB = *(const float4*)(bb + 4);
    float h0 = fmaxf(fmaf(dn, a0, bA.x), 0.f);
    float h1 = fmaxf(fmaf(dn, a1, bA.y), 0.f);
    float h2 = fmaxf(fmaf(dn, a2, bA.z), 0.f);
    float h3 = fmaxf(fmaf(dn, a3, bA.w), 0.f);
    float h4 = fmaxf(fmaf(dn, a4, bB.x), 0.f);
    float h5 = fmaxf(fmaf(dn, a5, bB.y), 0.f);
    float h6 = fmaxf(fmaf(dn, a6, bB.z), 0.f);
    float h7 = fmaxf(fmaf(dn, a7, bB.w), 0.f);
    // head dot: policy = lanes sl 0..15 (feats 0..127), value = lanes 16..31
    const float* ww = (sl < 16) ? (Wp + F) : (Wvh + F - 128);
    float4 wA = *(const float4*)ww;
    float4 wB = *(const float4*)(ww + 4);
    float p = h0 * wA.x + h1 * wA.y + h2 * wA.z + h3 * wA.w
            + h4 * wB.x + h5 * wB.y + h6 * wB.z + h7 * wB.w;
    p += __shfl_down(p, 8, 64);
    p += __shfl_down(p, 4, 64);
    p += __shfl_down(p, 2, 64);
    p += __shfl_down(p, 1, 64);
    if (sl == 0)  outm[node] = p + bp[0];
    if (sl == 16) outv[node] = p + bvh[0];
}

// ---------------- layer 2 GEMM via MFMA: t2 = h1 @ W^T (unscaled), fp16 ----------

__global__ __launch_bounds__(256)
void feat2(const __half* __restrict__ h, const __half* __restrict__ Wc,
           const __half* __restrict__ Wv, __half* __restrict__ tout, int N) {
    int lane = threadIdx.x & 63;
    int wave = threadIdx.x >> 6;
    int quad = lane >> 4, l16 = lane & 15;
    int n0 = blockIdx.x * 64 + wave * 16;
    int br = blockIdx.y;                       // 0 policy, 1 value
    const _Float16* W = (const _Float16*)(br ? Wv : Wc);
    int koff = br * 128;

    const _Float16* arow = (const _Float16*)h + (size_t)(n0 + l16) * 256 + koff + quad * 8;
    half8 a0 = *(const half8*)(arow + 0);
    half8 a1 = *(const half8*)(arow + 32);
    half8 a2 = *(const half8*)(arow + 64);
    half8 a3 = *(const half8*)(arow + 96);

    _Float16* to = (_Float16*)tout;
#pragma unroll
    for (int jj = 0; jj < 8; ++jj) {
        const _Float16* wrow = W + (size_t)(jj * 16 + l16) * 128 + quad * 8;
        half8 b0 = *(const half8*)(wrow + 0);
        half8 b1 = *(const half8*)(wrow + 32);
        half8 b2 = *(const half8*)(wrow + 64);
        half8 b3 = *(const half8*)(wrow + 96);
        f32x4 acc = {0.f, 0.f, 0.f, 0.f};
        acc = __builtin_amdgcn_mfma_f32_16x16x32_f16(a0, b0, acc, 0, 0, 0);
        acc = __builtin_amdgcn_mfma_f32_16x16x32_f16(a1, b1, acc, 0, 0, 0);
        acc = __builtin_amdgcn_mfma_f32_16x16x32_f16(a2, b2, acc, 0, 0, 0);
        acc = __builtin_amdgcn_mfma_f32_16x16x32_f16(a3, b3, acc, 0, 0, 0);
        int fo = koff + jj * 16 + l16;
#pragma unroll
        for (int r = 0; r < 4; ++r) {
            int node = n0 + quad * 4 + r;
            if (node < N)
                to[(size_t)node * 256 + fo] = (_Float16)acc[r];
        }
    }
}

// ---------------- launch ---------------------------------------------------------

extern "C" void kernel_launch(void* const* d_in, const int* in_sizes, int n_in,
                              void* d_out, int out_size, void* d_ws, size_t ws_size,
                              hipStream_t stream) {
    const float* x   = (const float*)d_in[0];
    const int*   ei  = (const int*)  d_in[1];
    const float* Wc1 = (const float*)d_in[2];
    const float* bc1 = (const float*)d_in[3];
    const float* Wc2 = (const float*)d_in[4];
    const float* bc2 = (const float*)d_in[5];
    const float* Wp  = (const float*)d_in[6];
    const float* bp  = (const float*)d_in[7];
    const float* Wv1 = (const float*)d_in[8];
    const float* bv1 = (const float*)d_in[9];
    const float* Wv2 = (const float*)d_in[10];
    const float* bv2 = (const float*)d_in[11];
    const float* Wvh = (const float*)d_in[12];
    const float* bvh = (const float*)d_in[13];

    const int N = in_sizes[0] / 16;   // 50000
    const int E = in_sizes[1] / 2;    // 800000
    const int Npad = (N + 63) & ~63;

    size_t off = 0;
    auto alloc = [&](size_t bytes) -> void* {
        void* p = (char*)d_ws + off;
        off += (bytes + 255) & ~(size_t)255;
        return p;
    };
    int*    cnt    = (int*)alloc((size_t)(N + 64) * sizeof(int));
    int*    flags  = cnt + N;                    // 13 lookback flags, same memset
    int*    pos    = (int*)alloc((size_t)E * sizeof(int));
    int*    rowptr = (int*)alloc((size_t)(N + 1) * sizeof(int));
    float*  dis    = (float*)alloc((size_t)Npad * sizeof(float));
    ull*    rec    = (ull*)alloc((size_t)E * sizeof(ull));           // 6.4 MB
    __half* Wch    = (__half*)alloc(128 * 128 * sizeof(__half));
    __half* Wvh2   = (__half*)alloc(128 * 128 * sizeof(__half));
    __half* tbuf   = (__half*)alloc((size_t)Npad * 256 * sizeof(__half)); // 25.6 MB
    __half* hbuf   = (__half*)alloc((size_t)Npad * 256 * sizeof(__half)); // 25.6 MB

    float* outm = (float*)d_out;
    float* outv = outm + N;

    const int nbE = (E + TPB - 1) / TPB;      // 3125
    const int nbF = (N + 15) / 16;            // 3125
    const int nbS = (N + SCAN_T * SCAN_PER - 1) / (SCAN_T * SCAN_PER);  // 13

    (void)hipMemsetAsync(cnt, 0, (size_t)(N + 64) * sizeof(int), stream);

    fused_prep<<<nbE + nbF + 64, TPB, 0, stream>>>(ei, cnt, pos, x, Wc1, Wv1, tbuf,
                                                   Wc2, Wv2, Wch, Wvh2,
                                                   N, E, nbE, nbF);
    scan_lookback<<<nbS, SCAN_T, 0, stream>>>(cnt, rowptr, dis, flags, N, E);
    fill_csr<<<nbE, TPB, 0, stream>>>(ei, rowptr, pos, dis, rec, E);

    agg1<<<(N + 7) / 8, TPB, 0, stream>>>((const uint4*)tbuf, rowptr, rec, dis,
                                          bc1, bv1, (uint4*)hbuf, N);
    feat2<<<dim3((N + 63) / 64, 2), TPB, 0, stream>>>(hbuf, Wch, Wvh2, tbuf, N);
    agg2<<<(N + 7) / 8, TPB, 0, stream>>>((const uint4*)tbuf, rowptr, rec, dis,
                                          bc2, bv2, Wp, bp, Wvh, bvh,
                                          outm, outv, N);
}

// Round 9
// 265.608 us; speedup vs baseline: 2.8373x; 1.1585x over previous
//
#include <hip/hip_runtime.h>
#include <hip/hip_bf16.h>
#include <hip/hip_fp16.h>

#define TPB 256

typedef _Float16 half8 __attribute__((ext_vector_type(8)));
typedef float f32x4 __attribute__((ext_vector_type(4)));
typedef unsigned long long ull;

// ---------------- prep: edge count (+pos), W2 -> fp16 ----------------------------

__global__ void fused_prep(const int* __restrict__ ei, int* __restrict__ cnt,
                           int* __restrict__ pos,
                           const float* __restrict__ Wc2, const float* __restrict__ Wv2,
                           __half* __restrict__ Wch, __half* __restrict__ Wvh2,
                           int E, int nbE) {
    int bid = blockIdx.x;
    int t = threadIdx.x;
    if (bid < nbE) {
        int e = bid * TPB + t;
        if (e < E) {
            int d = ei[E + e];
            pos[e] = atomicAdd(&cnt[d], 1);
        }
    } else {
        int i = (bid - nbE) * TPB + t;
        if (i < 128 * 128) {
            Wch[i]  = __float2half_rn(Wc2[i]);
            Wvh2[i] = __float2half_rn(Wv2[i]);
        }
    }
}

// ---------------- single-kernel scan (decoupled lookback, 13 co-resident blocks) -

#define SCAN_T 1024
#define SCAN_PER 4

__global__ __launch_bounds__(1024)
void scan_lookback(const int* __restrict__ cnt, int* __restrict__ rowptr,
                   float* __restrict__ dis, int* __restrict__ flags,
                   int N, int E) {
    __shared__ int sd[SCAN_T];
    __shared__ int s_prev;
    int t = threadIdx.x, b = blockIdx.x;
    int base = b * (SCAN_T * SCAN_PER) + t * SCAN_PER;
    int v[SCAN_PER];
    int s = 0;
#pragma unroll
    for (int k = 0; k < SCAN_PER; ++k) {
        int i = base + k;
        v[k] = (i < N) ? cnt[i] : 0;
        s += v[k];
    }
    sd[t] = s;
    __syncthreads();
    for (int off = 1; off < SCAN_T; off <<= 1) {
        int x = 0;
        if (t >= off) x = sd[t - off];
        __syncthreads();
        sd[t] += x;
        __syncthreads();
    }
    int excl = sd[t] - s;
    if (t == 0) {
        int prev = 0;
        if (b > 0) {
            int f;
            while ((f = __hip_atomic_load(flags + b - 1, __ATOMIC_ACQUIRE,
                                          __HIP_MEMORY_SCOPE_AGENT)) == 0) {}
            prev = f - 1;
        }
        __hip_atomic_store(flags + b, prev + sd[SCAN_T - 1] + 1,
                           __ATOMIC_RELEASE, __HIP_MEMORY_SCOPE_AGENT);
        s_prev = prev;
    }
    __syncthreads();
    int run = s_prev + excl;
#pragma unroll
    for (int k = 0; k < SCAN_PER; ++k) {
        int i = base + k;
        if (i < N) {
            rowptr[i] = run;
            dis[i] = rsqrtf((float)(v[k] + 1));
            run += v[k];
        }
    }
    if (b == 0 && t == 0) rowptr[N] = E;
}

// ---------------- CSR fill (atomic-free): rec[e] = {dis[src] : src} --------------

__global__ void fill_csr(const int* __restrict__ ei, const int* __restrict__ rowptr,
                         const int* __restrict__ pos, const float* __restrict__ dis,
                         ull* __restrict__ rec, int E) {
    int e = blockIdx.x * TPB + threadIdx.x;
    if (e >= E) return;
    int s = ei[e], d = ei[E + e];
    int p = rowptr[d] + pos[e];
    rec[p] = ((ull)__float_as_uint(dis[s]) << 32) | (unsigned)s;
}

// ---------------- layer 1, agg-first (linearity): ------------------------------
// xagg[i] = dis_i*(sum_s dis_s x_s + dis_i x_i)  (16-dim fp32 gather, table 3.2 MB
// = L2-resident per XCD), then h1 = relu(xagg @ W1^T + b) -> fp16, both branches.
// Block = 64 nodes: gather phase = 4 waves x 16 lane-groups of 4 (lane = float4),
// matmul phase = 256 threads = 256 output cols.

__global__ __launch_bounds__(256)
void agg1_feat1(const float* __restrict__ x, const int* __restrict__ rowptr,
                const ull* __restrict__ rec, const float* __restrict__ dis,
                const float* __restrict__ Wc1, const float* __restrict__ bc1,
                const float* __restrict__ Wv1, const float* __restrict__ bv1,
                __half* __restrict__ h1, int N) {
    __shared__ float xt[64][16];
    int tid = threadIdx.x;
    int wave = tid >> 6, lane = tid & 63;
    int g = lane >> 2, q = lane & 3;
    int n = wave * 16 + g;                    // 0..63 within block
    int node = blockIdx.x * 64 + n;
    if (node < N) {
        float dn = dis[node];
        float4 xs = *(const float4*)(x + (size_t)node * 16 + q * 4);
        float ax = dn * xs.x, ay = dn * xs.y, az = dn * xs.z, aw = dn * xs.w;
        int e = rowptr[node], end = rowptr[node + 1];
        const ull sent = (ull)(unsigned)node;     // ds = +0 -> no contribution
        ull r0 = (e < end) ? rec[e] : sent;
        ull r1 = (e + 1 < end) ? rec[e + 1] : sent;
        for (; e < end; e += 2) {
            int s0 = (int)(unsigned)r0, s1 = (int)(unsigned)r1;
            float d0 = __uint_as_float((unsigned)(r0 >> 32));
            float d1 = __uint_as_float((unsigned)(r1 >> 32));
            float4 x0 = *(const float4*)(x + (size_t)s0 * 16 + q * 4);
            float4 x1 = *(const float4*)(x + (size_t)s1 * 16 + q * 4);
            int en = e + 2;
            r0 = (en < end) ? rec[en] : sent;
            r1 = (en + 1 < end) ? rec[en + 1] : sent;
            ax = fmaf(d0, x0.x, fmaf(d1, x1.x, ax));
            ay = fmaf(d0, x0.y, fmaf(d1, x1.y, ay));
            az = fmaf(d0, x0.z, fmaf(d1, x1.z, az));
            aw = fmaf(d0, x0.w, fmaf(d1, x1.w, aw));
        }
        float4 o = make_float4(dn * ax, dn * ay, dn * az, dn * aw);
        *(float4*)(&xt[n][q * 4]) = o;
    }
    __syncthreads();
    // matmul phase: thread tid = output col (0..127 policy, 128..255 value)
    const float* wrow = (tid < 128) ? (Wc1 + tid * 16) : (Wv1 + (tid - 128) * 16);
    float bias = (tid < 128) ? bc1[tid] : bv1[tid - 128];
    float4 w0 = *(const float4*)(wrow + 0);
    float4 w1 = *(const float4*)(wrow + 4);
    float4 w2 = *(const float4*)(wrow + 8);
    float4 w3 = *(const float4*)(wrow + 12);
    int nmax = N - blockIdx.x * 64;
    if (nmax > 64) nmax = 64;
    for (int nn = 0; nn < nmax; ++nn) {
        const float* xr = xt[nn];
        float s = w0.x * xr[0] + w0.y * xr[1] + w0.z * xr[2] + w0.w * xr[3]
                + w1.x * xr[4] + w1.y * xr[5] + w1.z * xr[6] + w1.w * xr[7]
                + w2.x * xr[8] + w2.y * xr[9] + w2.z * xr[10] + w2.w * xr[11]
                + w3.x * xr[12] + w3.y * xr[13] + w3.z * xr[14] + w3.w * xr[15];
        h1[(size_t)(blockIdx.x * 64 + nn) * 256 + tid] =
            __float2half_rn(fmaxf(s + bias, 0.f));
    }
}

// ---------------- agg2 + heads: proven R8 high-MLP gather ------------------------
// wave = 2 nodes; lane = 16 B (8 fp16 feats); 4 edges in flight per half-wave

#define AGG_ACC(M, D)                                                               \
    {                                                                               \
        float2 f0 = __half22float2(*reinterpret_cast<const __half2*>(&M.x));        \
        float2 f1 = __half22float2(*reinterpret_cast<const __half2*>(&M.y));        \
        float2 f2 = __half22float2(*reinterpret_cast<const __half2*>(&M.z));        \
        float2 f3 = __half22float2(*reinterpret_cast<const __half2*>(&M.w));        \
        a0 = fmaf(D, f0.x, a0); a1 = fmaf(D, f0.y, a1);                             \
        a2 = fmaf(D, f1.x, a2); a3 = fmaf(D, f1.y, a3);                             \
        a4 = fmaf(D, f2.x, a4); a5 = fmaf(D, f2.y, a5);                             \
        a6 = fmaf(D, f3.x, a6); a7 = fmaf(D, f3.y, a7);                             \
    }

__global__ void agg2(const uint4* __restrict__ tin, const int* __restrict__ rowptr,
                     const ull* __restrict__ rec, const float* __restrict__ dis,
                     const float* __restrict__ bc, const float* __restrict__ bv,
                     const float* __restrict__ Wp, const float* __restrict__ bp,
                     const float* __restrict__ Wvh, const float* __restrict__ bvh,
                     float* __restrict__ outm, float* __restrict__ outv, int N) {
    int node = blockIdx.x * 8 + ((threadIdx.x >> 6) << 1) + ((threadIdx.x & 63) >> 5);
    if (node >= N) return;
    int sl = threadIdx.x & 31;
    float dn = dis[node];
    float a0, a1, a2, a3, a4, a5, a6, a7;
    {
        uint4 ms = tin[(size_t)node * 32 + sl];
        float2 s0 = __half22float2(*reinterpret_cast<const __half2*>(&ms.x));
        float2 s1 = __half22float2(*reinterpret_cast<const __half2*>(&ms.y));
        float2 s2 = __half22float2(*reinterpret_cast<const __half2*>(&ms.z));
        float2 s3 = __half22float2(*reinterpret_cast<const __half2*>(&ms.w));
        a0 = dn * s0.x; a1 = dn * s0.y; a2 = dn * s1.x; a3 = dn * s1.y;
        a4 = dn * s2.x; a5 = dn * s2.y; a6 = dn * s3.x; a7 = dn * s3.y;
    }
    int e = rowptr[node], end = rowptr[node + 1];
    const ull sent = (ull)(unsigned)node;
    ull r0 = (e + 0 < end) ? rec[e + 0] : sent;
    ull r1 = (e + 1 < end) ? rec[e + 1] : sent;
    ull r2 = (e + 2 < end) ? rec[e + 2] : sent;
    ull r3 = (e + 3 < end) ? rec[e + 3] : sent;
    for (; e < end; e += 4) {
        uint4 m0 = tin[(size_t)(unsigned)r0 * 32 + sl];
        uint4 m1 = tin[(size_t)(unsigned)r1 * 32 + sl];
        uint4 m2 = tin[(size_t)(unsigned)r2 * 32 + sl];
        uint4 m3 = tin[(size_t)(unsigned)r3 * 32 + sl];
        float d0 = __uint_as_float((unsigned)(r0 >> 32));
        float d1 = __uint_as_float((unsigned)(r1 >> 32));
        float d2 = __uint_as_float((unsigned)(r2 >> 32));
        float d3 = __uint_as_float((unsigned)(r3 >> 32));
        int en = e + 4;
        r0 = (en + 0 < end) ? rec[en + 0] : sent;
        r1 = (en + 1 < end) ? rec[en + 1] : sent;
        r2 = (en + 2 < end) ? rec[en + 2] : sent;
        r3 = (en + 3 < end) ? rec[en + 3] : sent;
        AGG_ACC(m0, d0) AGG_ACC(m1, d1) AGG_ACC(m2, d2) AGG_ACC(m3, d3)
    }
    int F = sl * 8;
    const float* bb = (F < 128) ? (bc + F) : (bv + F - 128);
    float4 bA = *(const float4*)bb;
    float4 bB = *(const float4*)(bb + 4);
    float h0 = fmaxf(fmaf(dn, a0, bA.x), 0.f);
    float h1 = fmaxf(fmaf(dn, a1, bA.y), 0.f);
    float h2 = fmaxf(fmaf(dn, a2, bA.z), 0.f);
    float h3 = fmaxf(fmaf(dn, a3, bA.w), 0.f);
    float h4 = fmaxf(fmaf(dn, a4, bB.x), 0.f);
    float h5 = fmaxf(fmaf(dn, a5, bB.y), 0.f);
    float h6 = fmaxf(fmaf(dn, a6, bB.z), 0.f);
    float h7 = fmaxf(fmaf(dn, a7, bB.w), 0.f);
    const float* ww = (sl < 16) ? (Wp + F) : (Wvh + F - 128);
    float4 wA = *(const float4*)ww;
    float4 wB = *(const float4*)(ww + 4);
    float p = h0 * wA.x + h1 * wA.y + h2 * wA.z + h3 * wA.w
            + h4 * wB.x + h5 * wB.y + h6 * wB.z + h7 * wB.w;
    p += __shfl_down(p, 8, 64);
    p += __shfl_down(p, 4, 64);
    p += __shfl_down(p, 2, 64);
    p += __shfl_down(p, 1, 64);
    if (sl == 0)  outm[node] = p + bp[0];
    if (sl == 16) outv[node] = p + bvh[0];
}

// ---------------- layer 2 GEMM via MFMA: t2 = h1 @ W^T (unscaled), fp16 ----------

__global__ __launch_bounds__(256)
void feat2(const __half* __restrict__ h, const __half* __restrict__ Wc,
           const __half* __restrict__ Wv, __half* __restrict__ tout, int N) {
    int lane = threadIdx.x & 63;
    int wave = threadIdx.x >> 6;
    int quad = lane >> 4, l16 = lane & 15;
    int n0 = blockIdx.x * 64 + wave * 16;
    int br = blockIdx.y;                       // 0 policy, 1 value
    const _Float16* W = (const _Float16*)(br ? Wv : Wc);
    int koff = br * 128;

    const _Float16* arow = (const _Float16*)h + (size_t)(n0 + l16) * 256 + koff + quad * 8;
    half8 a0 = *(const half8*)(arow + 0);
    half8 a1 = *(const half8*)(arow + 32);
    half8 a2 = *(const half8*)(arow + 64);
    half8 a3 = *(const half8*)(arow + 96);

    _Float16* to = (_Float16*)tout;
#pragma unroll
    for (int jj = 0; jj < 8; ++jj) {
        const _Float16* wrow = W + (size_t)(jj * 16 + l16) * 128 + quad * 8;
        half8 b0 = *(const half8*)(wrow + 0);
        half8 b1 = *(const half8*)(wrow + 32);
        half8 b2 = *(const half8*)(wrow + 64);
        half8 b3 = *(const half8*)(wrow + 96);
        f32x4 acc = {0.f, 0.f, 0.f, 0.f};
        acc = __builtin_amdgcn_mfma_f32_16x16x32_f16(a0, b0, acc, 0, 0, 0);
        acc = __builtin_amdgcn_mfma_f32_16x16x32_f16(a1, b1, acc, 0, 0, 0);
        acc = __builtin_amdgcn_mfma_f32_16x16x32_f16(a2, b2, acc, 0, 0, 0);
        acc = __builtin_amdgcn_mfma_f32_16x16x32_f16(a3, b3, acc, 0, 0, 0);
        int fo = koff + jj * 16 + l16;
#pragma unroll
        for (int r = 0; r < 4; ++r) {
            int node = n0 + quad * 4 + r;
            if (node < N)
                to[(size_t)node * 256 + fo] = (_Float16)acc[r];
        }
    }
}

// ---------------- launch ---------------------------------------------------------

extern "C" void kernel_launch(void* const* d_in, const int* in_sizes, int n_in,
                              void* d_out, int out_size, void* d_ws, size_t ws_size,
                              hipStream_t stream) {
    const float* x   = (const float*)d_in[0];
    const int*   ei  = (const int*)  d_in[1];
    const float* Wc1 = (const float*)d_in[2];
    const float* bc1 = (const float*)d_in[3];
    const float* Wc2 = (const float*)d_in[4];
    const float* bc2 = (const float*)d_in[5];
    const float* Wp  = (const float*)d_in[6];
    const float* bp  = (const float*)d_in[7];
    const float* Wv1 = (const float*)d_in[8];
    const float* bv1 = (const float*)d_in[9];
    const float* Wv2 = (const float*)d_in[10];
    const float* bv2 = (const float*)d_in[11];
    const float* Wvh = (const float*)d_in[12];
    const float* bvh = (const float*)d_in[13];

    const int N = in_sizes[0] / 16;   // 50000
    const int E = in_sizes[1] / 2;    // 800000
    const int Npad = (N + 63) & ~63;

    size_t off = 0;
    auto alloc = [&](size_t bytes) -> void* {
        void* p = (char*)d_ws + off;
        off += (bytes + 255) & ~(size_t)255;
        return p;
    };
    int*    cnt    = (int*)alloc((size_t)(N + 64) * sizeof(int));
    int*    flags  = cnt + N;                    // 13 lookback flags, same memset
    int*    pos    = (int*)alloc((size_t)E * sizeof(int));
    int*    rowptr = (int*)alloc((size_t)(N + 1) * sizeof(int));
    float*  dis    = (float*)alloc((size_t)Npad * sizeof(float));
    ull*    rec    = (ull*)alloc((size_t)E * sizeof(ull));           // 6.4 MB
    __half* Wch    = (__half*)alloc(128 * 128 * sizeof(__half));
    __half* Wvh2   = (__half*)alloc(128 * 128 * sizeof(__half));
    __half* tbuf   = (__half*)alloc((size_t)Npad * 256 * sizeof(__half)); // 25.6 MB
    __half* hbuf   = (__half*)alloc((size_t)Npad * 256 * sizeof(__half)); // 25.6 MB

    float* outm = (float*)d_out;
    float* outv = outm + N;

    const int nbE = (E + TPB - 1) / TPB;      // 3125
    const int nbS = (N + SCAN_T * SCAN_PER - 1) / (SCAN_T * SCAN_PER);  // 13

    (void)hipMemsetAsync(cnt, 0, (size_t)(N + 64) * sizeof(int), stream);

    fused_prep<<<nbE + 64, TPB, 0, stream>>>(ei, cnt, pos, Wc2, Wv2, Wch, Wvh2,
                                             E, nbE);
    scan_lookback<<<nbS, SCAN_T, 0, stream>>>(cnt, rowptr, dis, flags, N, E);
    fill_csr<<<nbE, TPB, 0, stream>>>(ei, rowptr, pos, dis, rec, E);

    // layer 1: gather x (L2-resident 3.2 MB table) then matmul -> hbuf (fp16)
    agg1_feat1<<<(N + 63) / 64, TPB, 0, stream>>>(x, rowptr, rec, dis,
                                                  Wc1, bc1, Wv1, bv1, hbuf, N);
    // layer 2: MFMA transform -> tbuf, gather + heads
    feat2<<<dim3((N + 63) / 64, 2), TPB, 0, stream>>>(hbuf, Wch, Wvh2, tbuf, N);
    agg2<<<(N + 7) / 8, TPB, 0, stream>>>((const uint4*)tbuf, rowptr, rec, dis,
                                          bc2, bv2, Wp, bp, Wvh, bvh,
                                          outm, outv, N);
}